// Round 8
// baseline (492.082 us; speedup 1.0000x reference)
//
#include <hip/hip_runtime.h>
#include <hip/hip_bf16.h>
#include <stdint.h>

typedef unsigned short u16;
typedef __attribute__((ext_vector_type(8))) short short8;   // 8 bf16 (4 VGPRs)
typedef __attribute__((ext_vector_type(4))) float f32x4;

union B8 { short8 v; u16 u[8]; };
union U4 { unsigned long long q; u16 u[4]; };

__device__ __forceinline__ float b2f(u16 b) {
  union { unsigned int i; float f; } x; x.i = ((unsigned int)b) << 16; return x.f;
}
__device__ __forceinline__ u16 f2b(float f) {
  __hip_bfloat16 h = __float2bfloat16(f);
  return *reinterpret_cast<u16*>(&h);
}

// async global->LDS, 16B/lane, LDS dest = wave-uniform base + lane*16 [m97]
#define GLOAD_LDS16(gp, lp)                                                  \
  __builtin_amdgcn_global_load_lds(                                          \
      (const __attribute__((address_space(1))) unsigned int*)(gp),           \
      (__attribute__((address_space(3))) unsigned int*)(lp), 16, 0, 0)

// ---------------- convert fp32 -> bf16 (elementwise, n % 1024 == 0) --------
__global__ __launch_bounds__(256) void cvt_f2b(const float* __restrict__ src,
                                               u16* __restrict__ dst) {
  size_t i = ((size_t)blockIdx.x * 256 + threadIdx.x) * 4;
  f32x4 v = *(const f32x4*)(src + i);
  U4 o;
#pragma unroll
  for (int j = 0; j < 4; ++j) o.u[j] = f2b(v[j]);
  *(unsigned long long*)(dst + i) = o.q;
}

// ---------------- convert + transpose: fp32 W[K][N] -> bf16 WT[N][K] -------
__global__ __launch_bounds__(256) void convt_w(const float* __restrict__ W,
                                               u16* __restrict__ WT,
                                               int K, int N) {
  int k  = blockIdx.x * 64 + (threadIdx.x & 63);
  int n8 = blockIdx.y * 32 + (threadIdx.x >> 6) * 8;
  const float* p = W + (size_t)k * N + n8;
  f32x4 a = *(const f32x4*)(p);
  f32x4 b = *(const f32x4*)(p + 4);
#pragma unroll
  for (int j = 0; j < 4; ++j) WT[(size_t)(n8 + j) * K + k] = f2b(a[j]);
#pragma unroll
  for (int j = 0; j < 4; ++j) WT[(size_t)(n8 + 4 + j) * K + k] = f2b(b[j]);
}

// ------ keys transpose: fp32 [H=4][K=64][P=2][N=64] -> [H][P][N][K] --------
__global__ __launch_bounds__(256) void convt_keys(const float* __restrict__ keys,
                                                  float* __restrict__ keysT) {
  int h = blockIdx.x, p = blockIdx.y;
  int k  = threadIdx.x >> 2;            // 0..63
  int n0 = (threadIdx.x & 3) * 16;      // 0,16,32,48
  const float* src = keys + ((size_t)(h * 64 + k) * 2 + p) * 64 + n0;
  float* dst = keysT + (((size_t)h * 2 + p) * 64) * 64 + k;
#pragma unroll
  for (int c = 0; c < 16; ++c)
    dst[(size_t)(n0 + c) * 64] = src[c];
}

// ---------------- small GEMM (q-projection): C = A @ BT^T ------------------
__global__ __launch_bounds__(256) void gemm_bf16(
    const u16* __restrict__ A, const u16* __restrict__ BT,
    const float* __restrict__ bias,
    u16* __restrict__ Cb, int M, int N, int K)
{
  __shared__ __attribute__((aligned(16))) u16 As[128 * 32];
  __shared__ __attribute__((aligned(16))) u16 Bs[128 * 32];
  int tid = threadIdx.x;
  int m0 = blockIdx.y * 128, n0 = blockIdx.x * 128;
  int wave = tid >> 6, lane = tid & 63;
  int wm = (wave >> 1) * 64, wn = (wave & 1) * 64;
  int quad = lane >> 4, r16 = lane & 15;
  int seg0 = wave * 2, seg1 = wave * 2 + 1;
  int srow = lane >> 2, scol = (lane & 3) * 8;

  const u16* a0 = A  + (size_t)(m0 + seg0 * 16 + srow) * K + scol;
  const u16* a1 = A  + (size_t)(m0 + seg1 * 16 + srow) * K + scol;
  const u16* b0 = BT + (size_t)(n0 + seg0 * 16 + srow) * K + scol;
  const u16* b1 = BT + (size_t)(n0 + seg1 * 16 + srow) * K + scol;

  f32x4 acc[4][4] = {};

  for (int k0 = 0; k0 < K; k0 += 32) {
    GLOAD_LDS16(a0 + k0, As + seg0 * 512);
    GLOAD_LDS16(a1 + k0, As + seg1 * 512);
    GLOAD_LDS16(b0 + k0, Bs + seg0 * 512);
    GLOAD_LDS16(b1 + k0, Bs + seg1 * 512);
    __syncthreads();
    short8 af[4], bfr[4];
#pragma unroll
    for (int i = 0; i < 4; ++i)
      af[i] = *(const short8*)(&As[(wm + i * 16 + r16) * 32 + quad * 8]);
#pragma unroll
    for (int j = 0; j < 4; ++j)
      bfr[j] = *(const short8*)(&Bs[(wn + j * 16 + r16) * 32 + quad * 8]);
#pragma unroll
    for (int i = 0; i < 4; ++i)
#pragma unroll
      for (int j = 0; j < 4; ++j)
        acc[i][j] = __builtin_amdgcn_mfma_f32_16x16x32_bf16(af[i], bfr[j], acc[i][j], 0, 0, 0);
    __syncthreads();
  }

  // C/D layout: col = lane&15, row = quad*4 + reg   [m89-verified]
#pragma unroll
  for (int i = 0; i < 4; ++i) {
    int row = m0 + wm + i * 16 + quad * 4;
#pragma unroll
    for (int j = 0; j < 4; ++j) {
      int col = n0 + wn + j * 16 + r16;
      float bv = bias ? bias[col] : 0.f;
#pragma unroll
      for (int r = 0; r < 4; ++r) {
        float v = acc[i][j][r] + bv;
        Cb[(size_t)(row + r) * N + col] = f2b(v);
      }
    }
  }
}

// ======== gemm_eb: m97-structure GEMM + fused epilogue, XCD-aware [T1] =====
// Single accumulator (64 AGPR) -> 3 waves/SIMD (vs gemm_gu's 128-AGPR dual
// acc capped at 2). XCD decode: lid&7 = XCD; each XCD owns 16 m-rows x one
// 8-wide n-chunk -> A panels 4MB + B chunk 2MB mostly L2-resident.
// mode 0: C = bf16(acc + bias); mode 1: C = bf16(silu(acc+bias) * U).
__global__ __launch_bounds__(256) void gemm_eb(
    const u16* __restrict__ A, const u16* __restrict__ BT,
    const float* __restrict__ bias, const u16* __restrict__ U,
    u16* __restrict__ C, int M, int N, int K, int mode)
{
  __shared__ __attribute__((aligned(16))) u16 As[128 * 32];
  __shared__ __attribute__((aligned(16))) u16 Bs[128 * 32];
  int tid = threadIdx.x;

  int lid = blockIdx.y * gridDim.x + blockIdx.x;
  int total = gridDim.x * gridDim.y;
  int n_blk, m_blk;
  if ((total & 63) == 0 && (gridDim.x & 7) == 0) {
    int x = lid & 7, s = lid >> 3;
    int gid = x * (total >> 6) + (s >> 3);   // group of 8 consecutive n-blocks
    int nch = gid / gridDim.y;
    m_blk = gid % gridDim.y;
    n_blk = nch * 8 + (s & 7);
  } else {
    n_blk = blockIdx.x; m_blk = blockIdx.y;
  }

  int m0 = m_blk * 128, n0 = n_blk * 128;
  int wave = tid >> 6, lane = tid & 63;
  int wm = (wave >> 1) * 64, wn = (wave & 1) * 64;
  int quad = lane >> 4, r16 = lane & 15;
  int seg0 = wave * 2, seg1 = wave * 2 + 1;
  int srow = lane >> 2, scol = (lane & 3) * 8;

  const u16* a0 = A  + (size_t)(m0 + seg0 * 16 + srow) * K + scol;
  const u16* a1 = A  + (size_t)(m0 + seg1 * 16 + srow) * K + scol;
  const u16* b0 = BT + (size_t)(n0 + seg0 * 16 + srow) * K + scol;
  const u16* b1 = BT + (size_t)(n0 + seg1 * 16 + srow) * K + scol;

  f32x4 acc[4][4] = {};

  for (int k0 = 0; k0 < K; k0 += 32) {
    GLOAD_LDS16(a0 + k0, As + seg0 * 512);
    GLOAD_LDS16(a1 + k0, As + seg1 * 512);
    GLOAD_LDS16(b0 + k0, Bs + seg0 * 512);
    GLOAD_LDS16(b1 + k0, Bs + seg1 * 512);
    __syncthreads();
    short8 af[4], bfr[4];
#pragma unroll
    for (int i = 0; i < 4; ++i)
      af[i] = *(const short8*)(&As[(wm + i * 16 + r16) * 32 + quad * 8]);
#pragma unroll
    for (int j = 0; j < 4; ++j)
      bfr[j] = *(const short8*)(&Bs[(wn + j * 16 + r16) * 32 + quad * 8]);
#pragma unroll
    for (int i = 0; i < 4; ++i)
#pragma unroll
      for (int j = 0; j < 4; ++j)
        acc[i][j] = __builtin_amdgcn_mfma_f32_16x16x32_bf16(af[i], bfr[j], acc[i][j], 0, 0, 0);
    __syncthreads();
  }

#pragma unroll
  for (int i = 0; i < 4; ++i) {
    int row0 = m0 + wm + i * 16 + quad * 4;
#pragma unroll
    for (int j = 0; j < 4; ++j) {
      int col = n0 + wn + j * 16 + r16;
      float bv = bias[col];
#pragma unroll
      for (int r = 0; r < 4; ++r) {
        int row = row0 + r;
        float g = acc[i][j][r] + bv;
        float h;
        if (mode == 1) {
          float u = b2f(U[(size_t)row * N + col]);
          h = (g / (1.f + __expf(-g))) * u;
        } else {
          h = g;
        }
        C[(size_t)row * N + col] = f2b(h);
      }
    }
  }
}

// -------- split-K down-GEMM: plain fp32 stores into per-slice partials -----
// XCD-aware decode [T1]: dispatch lid -> XCD x = lid&7 (round-robin HW
// heuristic). All 8 n-blocks of one (m,z) group land on ONE XCD (A-tile
// fetched once per XCD, not 8x), and each XCD gets contiguous m-tiles of a
// single z-slice (B-slice stays L2-resident). Bijective when (gy*S)%8==0.
__global__ __launch_bounds__(256) void gemm_dsk(
    const u16* __restrict__ A, const u16* __restrict__ BT,
    float* __restrict__ P, int M, int N, int K, int Kslice, int mOff)
{
  __shared__ __attribute__((aligned(16))) u16 As[128 * 32];
  __shared__ __attribute__((aligned(16))) u16 Bs[128 * 32];
  int tid = threadIdx.x;

  int lid = blockIdx.x + blockIdx.y * gridDim.x +
            blockIdx.z * gridDim.x * gridDim.y;
  int G = gridDim.y * gridDim.z;          // (m,z) groups; n = gridDim.x = 8
  int n_blk, m_blk, z_blk;
  if ((G & 7) == 0) {
    int x = lid & 7, s = lid >> 3;        // XCD, per-XCD slot
    int gid = x * (G >> 3) + (s >> 3);    // group handled by this XCD
    n_blk = s & 7;
    m_blk = gid % gridDim.y;
    z_blk = gid / gridDim.y;
  } else {
    n_blk = blockIdx.x; m_blk = blockIdx.y; z_blk = blockIdx.z;
  }

  int m0 = m_blk * 128, n0 = n_blk * 128;
  int kb = z_blk * Kslice, ke = kb + Kslice;
  int wave = tid >> 6, lane = tid & 63;
  int wm = (wave >> 1) * 64, wn = (wave & 1) * 64;
  int quad = lane >> 4, r16 = lane & 15;
  int seg0 = wave * 2, seg1 = wave * 2 + 1;
  int srow = lane >> 2, scol = (lane & 3) * 8;

  const u16* a0 = A  + (size_t)(m0 + seg0 * 16 + srow) * K + scol;
  const u16* a1 = A  + (size_t)(m0 + seg1 * 16 + srow) * K + scol;
  const u16* b0 = BT + (size_t)(n0 + seg0 * 16 + srow) * K + scol;
  const u16* b1 = BT + (size_t)(n0 + seg1 * 16 + srow) * K + scol;

  f32x4 acc[4][4] = {};

  for (int k0 = kb; k0 < ke; k0 += 32) {
    GLOAD_LDS16(a0 + k0, As + seg0 * 512);
    GLOAD_LDS16(a1 + k0, As + seg1 * 512);
    GLOAD_LDS16(b0 + k0, Bs + seg0 * 512);
    GLOAD_LDS16(b1 + k0, Bs + seg1 * 512);
    __syncthreads();
    short8 af[4], bfr[4];
#pragma unroll
    for (int i = 0; i < 4; ++i)
      af[i] = *(const short8*)(&As[(wm + i * 16 + r16) * 32 + quad * 8]);
#pragma unroll
    for (int j = 0; j < 4; ++j)
      bfr[j] = *(const short8*)(&Bs[(wn + j * 16 + r16) * 32 + quad * 8]);
#pragma unroll
    for (int i = 0; i < 4; ++i)
#pragma unroll
      for (int j = 0; j < 4; ++j)
        acc[i][j] = __builtin_amdgcn_mfma_f32_16x16x32_bf16(af[i], bfr[j], acc[i][j], 0, 0, 0);
    __syncthreads();
  }

  float* Pz = P + (size_t)z_blk * 4194304;   // 4096*1024 per slice
#pragma unroll
  for (int i = 0; i < 4; ++i) {
    int row = mOff + m0 + wm + i * 16 + quad * 4;
#pragma unroll
    for (int j = 0; j < 4; ++j) {
      int col = n0 + wn + j * 16 + r16;
#pragma unroll
      for (int r = 0; r < 4; ++r)
        Pz[(size_t)(row + r) * N + col] = acc[i][j][r];
    }
  }
}

// ------- fused reduce: out = sum_s P[s] + es + bd (N = 1024) ---------------
__global__ __launch_bounds__(256) void reduce_k(const float* __restrict__ part,
                                                int S,
                                                const float* __restrict__ es,
                                                const float* __restrict__ bd,
                                                float* __restrict__ out) {
  int t = blockIdx.x, c0 = threadIdx.x * 4;
  size_t off = (size_t)t * 1024 + c0;
  f32x4 a = *(const f32x4*)(es + off);
  for (int s = 0; s < S; ++s) {
    f32x4 p = *(const f32x4*)(part + (size_t)s * 4194304 + off);
#pragma unroll
    for (int c = 0; c < 4; ++c) a[c] += p[c];
  }
  f32x4 b = *(const f32x4*)(bd + c0);
  f32x4 o;
#pragma unroll
  for (int c = 0; c < 4; ++c) o[c] = a[c] + b[c];
  *(f32x4*)(out + off) = o;
}

// ======== bitonic top-8-of-64 network helpers (values spread 1/lane) =======
template<int NP>
__device__ __forceinline__ void sort8_desc(float (&v)[NP], int (&ii)[NP], int j) {
#pragma unroll
  for (int k = 2; k <= 8; k <<= 1) {
#pragma unroll
    for (int s = k >> 1; s > 0; s >>= 1) {
      bool desc  = (j & k) == 0;
      bool lower = (j & s) == 0;
#pragma unroll
      for (int p = 0; p < NP; ++p) {
        float vp = __shfl_xor(v[p], s);
        int   ip = __shfl_xor(ii[p], s);
        bool mf = (v[p] > vp) || (v[p] == vp && ii[p] < ip);
        bool keep = (desc == lower) ? mf : !mf;
        if (!keep) { v[p] = vp; ii[p] = ip; }
      }
    }
  }
}

template<int NP>
__device__ __forceinline__ void merge_top8(float (&v)[NP], int (&ii)[NP], int j) {
#pragma unroll
  for (int r = 0; r < 3; ++r) {
    int mask = (8 << r) | 7;     // partner group, mirrored position
#pragma unroll
    for (int p = 0; p < NP; ++p) {
      float vp = __shfl_xor(v[p], mask);
      int   ip = __shfl_xor(ii[p], mask);
      bool mf = (v[p] > vp) || (v[p] == vp && ii[p] < ip);
      if (!mf) { v[p] = vp; ii[p] = ip; }   // elementwise max -> bitonic seq
    }
#pragma unroll
    for (int s = 4; s > 0; s >>= 1) {       // bitonic merge, descending
      bool lower = (j & s) == 0;
#pragma unroll
      for (int p = 0; p < NP; ++p) {
        float vq = __shfl_xor(v[p], s);
        int   iq = __shfl_xor(ii[p], s);
        bool mf = (v[p] > vq) || (v[p] == vq && ii[p] < iq);
        bool keep = lower ? mf : !mf;
        if (!keep) { v[p] = vq; ii[p] = iq; }
      }
    }
  }
}

// ---------------- product-key retrieval (bitonic top-k, in-register) -------
__global__ __launch_bounds__(256) void retrieve_k(
    const u16*  __restrict__ q,      // bf16 [4096][512] = [t][p(2)][h(4)][n(64)]
    const float* __restrict__ keysT, // fp32 [4][2][64][64] = [h][p][n][k]
    int* __restrict__ idx_out,       // [4096][4][8]
    float* __restrict__ p_out)       // [4096][4][8]
{
  int t = blockIdx.x;
  int w = threadIdx.x >> 6, lane = threadIdx.x & 63;
  int j = lane & 7;

  float v[2]; int ii[2];
#pragma unroll
  for (int p = 0; p < 2; ++p) {
    const u16*   qp = q + (size_t)t * 512 + p * 256 + w * 64;   // broadcast
    const float* kp = keysT + ((size_t)(w * 2 + p) * 64) * 64 + lane;
    float s0 = 0.f, s1 = 0.f, s2 = 0.f, s3 = 0.f;   // 4-way fma ILP
#pragma unroll
    for (int n = 0; n < 64; n += 8) {
      B8 qv; qv.v = *(const short8*)(qp + n);
      s0 += b2f(qv.u[0]) * kp[(size_t)(n + 0) * 64];
      s1 += b2f(qv.u[1]) * kp[(size_t)(n + 1) * 64];
      s2 += b2f(qv.u[2]) * kp[(size_t)(n + 2) * 64];
      s3 += b2f(qv.u[3]) * kp[(size_t)(n + 3) * 64];
      s0 += b2f(qv.u[4]) * kp[(size_t)(n + 4) * 64];
      s1 += b2f(qv.u[5]) * kp[(size_t)(n + 5) * 64];
      s2 += b2f(qv.u[6]) * kp[(size_t)(n + 6) * 64];
      s3 += b2f(qv.u[7]) * kp[(size_t)(n + 7) * 64];
    }
    v[p] = (s0 + s1) + (s2 + s3); ii[p] = lane;
  }

  // phase 1: per-half top-8 of 64 (two interleaved networks)
  sort8_desc<2>(v, ii, j);
  merge_top8<2>(v, ii, j);

  // phase 2: 64 combo sums; groups pre-sorted (sy sorted), merge only
  float v2[1] = { __shfl(v[0], lane >> 3) + __shfl(v[1], lane & 7) };
  int  pos[1] = { lane };                   // combo position = tie-break key
  merge_top8<1>(v2, pos, j);

  int ex = __shfl(ii[0], pos[0] >> 3);
  int ey = __shfl(ii[1], pos[0] & 7);

  float m = __shfl(v2[0], 0);
  float e = __expf(v2[0] - m);
  float sum = e;
#pragma unroll
  for (int s = 4; s > 0; s >>= 1) sum += __shfl_xor(sum, s);

  if (lane < 8) {
    int o = (t * 4 + w) * 8 + lane;
    p_out[o]   = e / sum;
    idx_out[o] = ex * 64 + ey;
  }
}

// ---------------- expert gather + weighted sum (bf16 tables, fp32 acc) -----
__global__ __launch_bounds__(256) void expert_k(
    const u16* __restrict__ xb, const u16* __restrict__ downb,
    const u16* __restrict__ upb,
    const int* __restrict__ idx, const float* __restrict__ probs,
    float* __restrict__ es)     // [4096][1024] fp32
{
  __shared__ float acc_s[4][1024];   // 16 KB
  int t = blockIdx.x;
  int w = threadIdx.x >> 6, lane = threadIdx.x & 63;
  const size_t tb = (size_t)t * 1024;
  const int lo = lane * 8;

  B8 xv0, xv1;
  xv0.v = *(const short8*)(xb + tb + lo);
  xv1.v = *(const short8*)(xb + tb + 512 + lo);
  float xf[16];
#pragma unroll
  for (int c = 0; c < 8; ++c) { xf[c] = b2f(xv0.u[c]); xf[8 + c] = b2f(xv1.u[c]); }

  float a[16] = {};
#pragma unroll
  for (int e8 = 0; e8 < 8; ++e8) {
    int e = w * 8 + e8;
    int id = idx[t * 32 + e];
    const u16* dp = downb + (size_t)id * 1024;
    B8 d0, d1;
    d0.v = *(const short8*)(dp + lo);
    d1.v = *(const short8*)(dp + 512 + lo);
    float part = 0.f;
#pragma unroll
    for (int c = 0; c < 8; ++c)
      part += xf[c] * b2f(d0.u[c]) + xf[8 + c] * b2f(d1.u[c]);
#pragma unroll
    for (int off = 32; off; off >>= 1) part += __shfl_xor(part, off);
    float gate = (part / (1.f + __expf(-part))) * probs[t * 32 + e];
    const u16* upp = upb + (size_t)id * 1024;
    B8 u0, u1;
    u0.v = *(const short8*)(upp + lo);
    u1.v = *(const short8*)(upp + 512 + lo);
#pragma unroll
    for (int c = 0; c < 8; ++c) {
      a[c]     += gate * b2f(u0.u[c]);
      a[8 + c] += gate * b2f(u1.u[c]);
    }
  }
#pragma unroll
  for (int c = 0; c < 8; ++c) {
    acc_s[w][lo + c]       = a[c];
    acc_s[w][512 + lo + c] = a[8 + c];
  }
  __syncthreads();
  int d0i = threadIdx.x * 4;
  f32x4 s0 = *(const f32x4*)(&acc_s[0][d0i]);
  f32x4 s1 = *(const f32x4*)(&acc_s[1][d0i]);
  f32x4 s2 = *(const f32x4*)(&acc_s[2][d0i]);
  f32x4 s3 = *(const f32x4*)(&acc_s[3][d0i]);
  f32x4 o;
#pragma unroll
  for (int c = 0; c < 4; ++c) o[c] = (s0[c] + s1[c]) + (s2[c] + s3[c]);
  *(f32x4*)(es + tb + d0i) = o;
}

extern "C" void kernel_launch(void* const* d_in, const int* in_sizes, int n_in,
                              void* d_out, int out_size, void* d_ws, size_t ws_size,
                              hipStream_t stream)
{
  const float* x    = (const float*)d_in[0];
  const float* Wg   = (const float*)d_in[1];
  const float* bg   = (const float*)d_in[2];
  const float* Wu   = (const float*)d_in[3];
  const float* bu   = (const float*)d_in[4];
  const float* Wd   = (const float*)d_in[5];
  const float* bd   = (const float*)d_in[6];
  const float* Wq   = (const float*)d_in[7];
  const float* keys = (const float*)d_in[8];
  const float* down = (const float*)d_in[9];
  const float* up   = (const float*)d_in[10];
  float* out = (float*)d_out;

  // --- workspace layout (161 MB, r4-proven footprint) ---
  const size_t MB = 1048576;
  char* ws = (char*)d_ws;
  u16*   xb    = (u16*)(ws);                 // 8 MB  bf16 x [4096][1024]
  u16*   WgT   = (u16*)(ws + 8  * MB);       // 8 MB  bf16 [4096][1024]
  u16*   WuT   = (u16*)(ws + 16 * MB);       // 8 MB
  u16*   WdT   = (u16*)(ws + 24 * MB);       // 8 MB  bf16 [1024][4096]
  float* es    = (float*)(ws + 32 * MB);     // 16 MB fp32 [4096][1024]
  u16*   WqT   = (u16*)(ws + 32 * MB);       // 1 MB, aliases es head (dead first)
  u16*   qb    = (u16*)(ws + 34 * MB);       // 4 MB, aliases es (dead first)
  float* keysT = (float*)(ws + 47 * MB);     // 128 KB, aliases es tail (dead first)
  int*   idxb  = (int*)(ws + 48 * MB);       // 512 KB
  float* prb   = (float*)(ws + 48 * MB + 512 * 1024);
  u16*   downb = (u16*)(ws + 49 * MB);       // 8 MB bf16 [4096][1024]
  u16*   upb   = (u16*)(ws + 57 * MB);       // 8 MB
  float* part  = (float*)(ws + 65 * MB);     // 32 MB fp32 2x[4096][1024]
  u16*   Ub    = (u16*)(ws + 97 * MB);       // 32 MB bf16 [4096][4096]
  u16*   gb    = (u16*)(ws + 129 * MB);      // 32 MB bf16 [4096][4096]
  const int S = 2;

  // conversions (fp32 -> bf16; weights fused with transpose)
  cvt_f2b<<<4096, 256, 0, stream>>>(x, xb);
  cvt_f2b<<<4096, 256, 0, stream>>>(down, downb);
  cvt_f2b<<<4096, 256, 0, stream>>>(up, upb);
  convt_w<<<dim3(16, 16),  256, 0, stream>>>(Wq, WqT, 1024, 512);
  convt_w<<<dim3(16, 128), 256, 0, stream>>>(Wg, WgT, 1024, 4096);
  convt_w<<<dim3(16, 128), 256, 0, stream>>>(Wu, WuT, 1024, 4096);
  convt_w<<<dim3(64, 32),  256, 0, stream>>>(Wd, WdT, 4096, 1024);
  convt_keys<<<dim3(4, 2), 256, 0, stream>>>(keys, keysT);

  // retrieval chain: q = x@Wq -> topk experts -> es
  gemm_bf16<<<dim3(4, 32), 256, 0, stream>>>(xb, WqT, nullptr,
                                             qb, 4096, 512, 1024);
  retrieve_k<<<4096, 256, 0, stream>>>(qb, keysT, idxb, prb);
  expert_k<<<4096, 256, 0, stream>>>(xb, downb, upb, idxb, prb, es);

  // MLP chain (split gate/up, single-acc m97 structure + T1):
  //   Ub = x@Wu+bu ; gb = silu(x@Wg+bg)*Ub ; part[z] = gb@Wd ; out = sum+es+bd
  gemm_eb<<<dim3(32, 32), 256, 0, stream>>>(xb, WuT, bu, nullptr, Ub,
                                            4096, 4096, 1024, 0);
  gemm_eb<<<dim3(32, 32), 256, 0, stream>>>(xb, WgT, bg, Ub, gb,
                                            4096, 4096, 1024, 1);
  gemm_dsk<<<dim3(8, 32, S), 256, 0, stream>>>(gb, WdT, part,
                                               4096, 1024, 4096, 4096 / S, 0);
  reduce_k<<<4096, 256, 0, stream>>>(part, S, es, bd, out);
}

// Round 9
// 407.782 us; speedup vs baseline: 1.2067x; 1.2067x over previous
//
#include <hip/hip_runtime.h>
#include <hip/hip_bf16.h>
#include <stdint.h>

typedef unsigned short u16;
typedef __attribute__((ext_vector_type(8))) short short8;   // 8 bf16 (4 VGPRs)
typedef __attribute__((ext_vector_type(4))) float f32x4;

union B8 { short8 v; u16 u[8]; };
union U4 { unsigned long long q; u16 u[4]; };

__device__ __forceinline__ float b2f(u16 b) {
  union { unsigned int i; float f; } x; x.i = ((unsigned int)b) << 16; return x.f;
}
__device__ __forceinline__ u16 f2b(float f) {
  __hip_bfloat16 h = __float2bfloat16(f);
  return *reinterpret_cast<u16*>(&h);
}

// async global->LDS, 16B/lane, LDS dest = wave-uniform base + lane*16 [m97]
#define GLOAD_LDS16(gp, lp)                                                  \
  __builtin_amdgcn_global_load_lds(                                          \
      (const __attribute__((address_space(1))) unsigned int*)(gp),           \
      (__attribute__((address_space(3))) unsigned int*)(lp), 16, 0, 0)

// ---------------- convert fp32 -> bf16 (elementwise, n % 1024 == 0) --------
__global__ __launch_bounds__(256) void cvt_f2b(const float* __restrict__ src,
                                               u16* __restrict__ dst) {
  size_t i = ((size_t)blockIdx.x * 256 + threadIdx.x) * 4;
  f32x4 v = *(const f32x4*)(src + i);
  U4 o;
#pragma unroll
  for (int j = 0; j < 4; ++j) o.u[j] = f2b(v[j]);
  *(unsigned long long*)(dst + i) = o.q;
}

// ---------------- convert + transpose: fp32 W[K][N] -> bf16 WT[N][K] -------
__global__ __launch_bounds__(256) void convt_w(const float* __restrict__ W,
                                               u16* __restrict__ WT,
                                               int K, int N) {
  int k  = blockIdx.x * 64 + (threadIdx.x & 63);
  int n8 = blockIdx.y * 32 + (threadIdx.x >> 6) * 8;
  const float* p = W + (size_t)k * N + n8;
  f32x4 a = *(const f32x4*)(p);
  f32x4 b = *(const f32x4*)(p + 4);
#pragma unroll
  for (int j = 0; j < 4; ++j) WT[(size_t)(n8 + j) * K + k] = f2b(a[j]);
#pragma unroll
  for (int j = 0; j < 4; ++j) WT[(size_t)(n8 + 4 + j) * K + k] = f2b(b[j]);
}

// ------ keys transpose: fp32 [H=4][K=64][P=2][N=64] -> [H][P][N][K] --------
__global__ __launch_bounds__(256) void convt_keys(const float* __restrict__ keys,
                                                  float* __restrict__ keysT) {
  int h = blockIdx.x, p = blockIdx.y;
  int k  = threadIdx.x >> 2;            // 0..63
  int n0 = (threadIdx.x & 3) * 16;      // 0,16,32,48
  const float* src = keys + ((size_t)(h * 64 + k) * 2 + p) * 64 + n0;
  float* dst = keysT + (((size_t)h * 2 + p) * 64) * 64 + k;
#pragma unroll
  for (int c = 0; c < 16; ++c)
    dst[(size_t)(n0 + c) * 64] = src[c];
}

// ---------------- small GEMM (q-projection): C = A @ BT^T ------------------
__global__ __launch_bounds__(256) void gemm_bf16(
    const u16* __restrict__ A, const u16* __restrict__ BT,
    const float* __restrict__ bias,
    u16* __restrict__ Cb, int M, int N, int K)
{
  __shared__ __attribute__((aligned(16))) u16 As[128 * 32];
  __shared__ __attribute__((aligned(16))) u16 Bs[128 * 32];
  int tid = threadIdx.x;
  int m0 = blockIdx.y * 128, n0 = blockIdx.x * 128;
  int wave = tid >> 6, lane = tid & 63;
  int wm = (wave >> 1) * 64, wn = (wave & 1) * 64;
  int quad = lane >> 4, r16 = lane & 15;
  int seg0 = wave * 2, seg1 = wave * 2 + 1;
  int srow = lane >> 2, scol = (lane & 3) * 8;

  const u16* a0 = A  + (size_t)(m0 + seg0 * 16 + srow) * K + scol;
  const u16* a1 = A  + (size_t)(m0 + seg1 * 16 + srow) * K + scol;
  const u16* b0 = BT + (size_t)(n0 + seg0 * 16 + srow) * K + scol;
  const u16* b1 = BT + (size_t)(n0 + seg1 * 16 + srow) * K + scol;

  f32x4 acc[4][4] = {};

  for (int k0 = 0; k0 < K; k0 += 32) {
    GLOAD_LDS16(a0 + k0, As + seg0 * 512);
    GLOAD_LDS16(a1 + k0, As + seg1 * 512);
    GLOAD_LDS16(b0 + k0, Bs + seg0 * 512);
    GLOAD_LDS16(b1 + k0, Bs + seg1 * 512);
    __syncthreads();
    short8 af[4], bfr[4];
#pragma unroll
    for (int i = 0; i < 4; ++i)
      af[i] = *(const short8*)(&As[(wm + i * 16 + r16) * 32 + quad * 8]);
#pragma unroll
    for (int j = 0; j < 4; ++j)
      bfr[j] = *(const short8*)(&Bs[(wn + j * 16 + r16) * 32 + quad * 8]);
#pragma unroll
    for (int i = 0; i < 4; ++i)
#pragma unroll
      for (int j = 0; j < 4; ++j)
        acc[i][j] = __builtin_amdgcn_mfma_f32_16x16x32_bf16(af[i], bfr[j], acc[i][j], 0, 0, 0);
    __syncthreads();
  }

  // C/D layout: col = lane&15, row = quad*4 + reg   [m89-verified]
#pragma unroll
  for (int i = 0; i < 4; ++i) {
    int row = m0 + wm + i * 16 + quad * 4;
#pragma unroll
    for (int j = 0; j < 4; ++j) {
      int col = n0 + wn + j * 16 + r16;
      float bv = bias ? bias[col] : 0.f;
#pragma unroll
      for (int r = 0; r < 4; ++r) {
        float v = acc[i][j][r] + bv;
        Cb[(size_t)(row + r) * N + col] = f2b(v);
      }
    }
  }
}

// ------- fused gate+up GEMM, BK=64: H = silu(A@Bg^T+bg)*(A@Bu^T+bu) --------
// r8 lesson: K-step cost is drain-dominated and ~constant; maximize MFMA per
// drain. BK 32->64: 16 K-steps x 64 MFMA (was 32 x 32). LDS 48KB (3 blk/CU
// >= reg-limited 2). 128B rows would be a 16-way bank conflict [G4], so use
// the g9-verified XOR swizzle: global 16B-block ^= (row&7) on stage (LDS
// linear), same XOR on ds_read [rule #21; on-device-verified r6].
__global__ __launch_bounds__(256, 2) void gemm_gu(
    const u16* __restrict__ A, const u16* __restrict__ BgT,
    const u16* __restrict__ BuT,
    const float* __restrict__ bg, const float* __restrict__ bu,
    u16* __restrict__ H, int M, int N, int K)
{
  __shared__ __attribute__((aligned(16))) u16 As[128 * 64];
  __shared__ __attribute__((aligned(16))) u16 Gs[128 * 64];
  __shared__ __attribute__((aligned(16))) u16 Us[128 * 64];
  int tid = threadIdx.x;
  int m0 = blockIdx.y * 128, n0 = blockIdx.x * 128;
  int wave = tid >> 6, lane = tid & 63;
  int wm = (wave >> 1) * 64, wn = (wave & 1) * 64;
  int quad = lane >> 4, r16 = lane & 15;
  int s7 = r16 & 7;

  // staging: wave stages rows wave*32..+31 per matrix (4 loads of 8 rows);
  // lane -> row +(lane>>3), global 16B-block (lane&7)^(lane>>3)  [swizzle]
  int srow = lane >> 3;
  int scol = ((lane & 7) ^ srow) * 8;
  const u16* aG = A   + (size_t)(m0 + wave * 32 + srow) * K + scol;
  const u16* gG = BgT + (size_t)(n0 + wave * 32 + srow) * K + scol;
  const u16* uG = BuT + (size_t)(n0 + wave * 32 + srow) * K + scol;
  u16* lbase = (u16*)0;  // silence unused warnings pattern (not used)

  f32x4 ag[4][4] = {}, au[4][4] = {};

  for (int k0 = 0; k0 < K; k0 += 64) {
#pragma unroll
    for (int idx = 0; idx < 4; ++idx) {
      size_t go = (size_t)idx * 8 * K + k0;
      int lo = wave * 2048 + idx * 512;
      GLOAD_LDS16(aG + go, As + lo);
      GLOAD_LDS16(gG + go, Gs + lo);
      GLOAD_LDS16(uG + go, Us + lo);
    }
    __syncthreads();
#pragma unroll
    for (int kk = 0; kk < 2; ++kk) {
      short8 af[4], bfr[4];
#pragma unroll
      for (int i = 0; i < 4; ++i)
        af[i] = *(const short8*)(&As[(wm + i * 16 + r16) * 64
                                     + (((kk << 2) + quad) ^ s7) * 8]);
#pragma unroll
      for (int j = 0; j < 4; ++j)
        bfr[j] = *(const short8*)(&Gs[(wn + j * 16 + r16) * 64
                                      + (((kk << 2) + quad) ^ s7) * 8]);
#pragma unroll
      for (int i = 0; i < 4; ++i)
#pragma unroll
        for (int j = 0; j < 4; ++j)
          ag[i][j] = __builtin_amdgcn_mfma_f32_16x16x32_bf16(af[i], bfr[j], ag[i][j], 0, 0, 0);
#pragma unroll
      for (int j = 0; j < 4; ++j)
        bfr[j] = *(const short8*)(&Us[(wn + j * 16 + r16) * 64
                                      + (((kk << 2) + quad) ^ s7) * 8]);
#pragma unroll
      for (int i = 0; i < 4; ++i)
#pragma unroll
        for (int j = 0; j < 4; ++j)
          au[i][j] = __builtin_amdgcn_mfma_f32_16x16x32_bf16(af[i], bfr[j], au[i][j], 0, 0, 0);
    }
    __syncthreads();
  }
  (void)lbase;

#pragma unroll
  for (int i = 0; i < 4; ++i) {
    int row = m0 + wm + i * 16 + quad * 4;
#pragma unroll
    for (int j = 0; j < 4; ++j) {
      int col = n0 + wn + j * 16 + r16;
      float bgv = bg[col], buv = bu[col];
#pragma unroll
      for (int r = 0; r < 4; ++r) {
        float g = ag[i][j][r] + bgv;
        float u = au[i][j][r] + buv;
        float h = (g / (1.f + __expf(-g))) * u;
        H[(size_t)(row + r) * N + col] = f2b(h);
      }
    }
  }
}

// -------- split-K down-GEMM, BK=64, XCD-aware [T1, r7-proven] --------------
// 32 K-steps x 32 MFMA (was 64 x 16). Same swizzle as gemm_gu. LDS 32KB.
__global__ __launch_bounds__(256) void gemm_dsk(
    const u16* __restrict__ A, const u16* __restrict__ BT,
    float* __restrict__ P, int M, int N, int K, int Kslice, int mOff)
{
  __shared__ __attribute__((aligned(16))) u16 As[128 * 64];
  __shared__ __attribute__((aligned(16))) u16 Bs[128 * 64];
  int tid = threadIdx.x;

  int lid = blockIdx.x + blockIdx.y * gridDim.x +
            blockIdx.z * gridDim.x * gridDim.y;
  int G = gridDim.y * gridDim.z;          // (m,z) groups; n = gridDim.x = 8
  int n_blk, m_blk, z_blk;
  if ((G & 7) == 0) {
    int x = lid & 7, s = lid >> 3;        // XCD, per-XCD slot
    int gid = x * (G >> 3) + (s >> 3);    // group handled by this XCD
    n_blk = s & 7;
    m_blk = gid % gridDim.y;
    z_blk = gid / gridDim.y;
  } else {
    n_blk = blockIdx.x; m_blk = blockIdx.y; z_blk = blockIdx.z;
  }

  int m0 = m_blk * 128, n0 = n_blk * 128;
  int kb = z_blk * Kslice, ke = kb + Kslice;
  int wave = tid >> 6, lane = tid & 63;
  int wm = (wave >> 1) * 64, wn = (wave & 1) * 64;
  int quad = lane >> 4, r16 = lane & 15;
  int s7 = r16 & 7;

  int srow = lane >> 3;
  int scol = ((lane & 7) ^ srow) * 8;
  const u16* aG = A  + (size_t)(m0 + wave * 32 + srow) * K + scol;
  const u16* bG = BT + (size_t)(n0 + wave * 32 + srow) * K + scol;

  f32x4 acc[4][4] = {};

  for (int k0 = kb; k0 < ke; k0 += 64) {
#pragma unroll
    for (int idx = 0; idx < 4; ++idx) {
      size_t go = (size_t)idx * 8 * K + k0;
      int lo = wave * 2048 + idx * 512;
      GLOAD_LDS16(aG + go, As + lo);
      GLOAD_LDS16(bG + go, Bs + lo);
    }
    __syncthreads();
#pragma unroll
    for (int kk = 0; kk < 2; ++kk) {
      short8 af[4], bfr[4];
#pragma unroll
      for (int i = 0; i < 4; ++i)
        af[i] = *(const short8*)(&As[(wm + i * 16 + r16) * 64
                                     + (((kk << 2) + quad) ^ s7) * 8]);
#pragma unroll
      for (int j = 0; j < 4; ++j)
        bfr[j] = *(const short8*)(&Bs[(wn + j * 16 + r16) * 64
                                      + (((kk << 2) + quad) ^ s7) * 8]);
#pragma unroll
      for (int i = 0; i < 4; ++i)
#pragma unroll
        for (int j = 0; j < 4; ++j)
          acc[i][j] = __builtin_amdgcn_mfma_f32_16x16x32_bf16(af[i], bfr[j], acc[i][j], 0, 0, 0);
    }
    __syncthreads();
  }

  float* Pz = P + (size_t)z_blk * 4194304;   // 4096*1024 per slice
#pragma unroll
  for (int i = 0; i < 4; ++i) {
    int row = mOff + m0 + wm + i * 16 + quad * 4;
#pragma unroll
    for (int j = 0; j < 4; ++j) {
      int col = n0 + wn + j * 16 + r16;
#pragma unroll
      for (int r = 0; r < 4; ++r)
        Pz[(size_t)(row + r) * N + col] = acc[i][j][r];
    }
  }
}

// ------- fused reduce: out = sum_s P[s] + es + bd (N = 1024) ---------------
__global__ __launch_bounds__(256) void reduce_k(const float* __restrict__ part,
                                                int S,
                                                const float* __restrict__ es,
                                                const float* __restrict__ bd,
                                                float* __restrict__ out) {
  int t = blockIdx.x, c0 = threadIdx.x * 4;
  size_t off = (size_t)t * 1024 + c0;
  f32x4 a = *(const f32x4*)(es + off);
  for (int s = 0; s < S; ++s) {
    f32x4 p = *(const f32x4*)(part + (size_t)s * 4194304 + off);
#pragma unroll
    for (int c = 0; c < 4; ++c) a[c] += p[c];
  }
  f32x4 b = *(const f32x4*)(bd + c0);
  f32x4 o;
#pragma unroll
  for (int c = 0; c < 4; ++c) o[c] = a[c] + b[c];
  *(f32x4*)(out + off) = o;
}

// ======== bitonic top-8-of-64 network helpers (values spread 1/lane) =======
template<int NP>
__device__ __forceinline__ void sort8_desc(float (&v)[NP], int (&ii)[NP], int j) {
#pragma unroll
  for (int k = 2; k <= 8; k <<= 1) {
#pragma unroll
    for (int s = k >> 1; s > 0; s >>= 1) {
      bool desc  = (j & k) == 0;
      bool lower = (j & s) == 0;
#pragma unroll
      for (int p = 0; p < NP; ++p) {
        float vp = __shfl_xor(v[p], s);
        int   ip = __shfl_xor(ii[p], s);
        bool mf = (v[p] > vp) || (v[p] == vp && ii[p] < ip);
        bool keep = (desc == lower) ? mf : !mf;
        if (!keep) { v[p] = vp; ii[p] = ip; }
      }
    }
  }
}

template<int NP>
__device__ __forceinline__ void merge_top8(float (&v)[NP], int (&ii)[NP], int j) {
#pragma unroll
  for (int r = 0; r < 3; ++r) {
    int mask = (8 << r) | 7;     // partner group, mirrored position
#pragma unroll
    for (int p = 0; p < NP; ++p) {
      float vp = __shfl_xor(v[p], mask);
      int   ip = __shfl_xor(ii[p], mask);
      bool mf = (v[p] > vp) || (v[p] == vp && ii[p] < ip);
      if (!mf) { v[p] = vp; ii[p] = ip; }   // elementwise max -> bitonic seq
    }
#pragma unroll
    for (int s = 4; s > 0; s >>= 1) {       // bitonic merge, descending
      bool lower = (j & s) == 0;
#pragma unroll
      for (int p = 0; p < NP; ++p) {
        float vq = __shfl_xor(v[p], s);
        int   iq = __shfl_xor(ii[p], s);
        bool mf = (v[p] > vq) || (v[p] == vq && ii[p] < iq);
        bool keep = lower ? mf : !mf;
        if (!keep) { v[p] = vq; ii[p] = iq; }
      }
    }
  }
}

// ---------------- product-key retrieval (bitonic top-k, in-register) -------
__global__ __launch_bounds__(256) void retrieve_k(
    const u16*  __restrict__ q,      // bf16 [4096][512] = [t][p(2)][h(4)][n(64)]
    const float* __restrict__ keysT, // fp32 [4][2][64][64] = [h][p][n][k]
    int* __restrict__ idx_out,       // [4096][4][8]
    float* __restrict__ p_out)       // [4096][4][8]
{
  int t = blockIdx.x;
  int w = threadIdx.x >> 6, lane = threadIdx.x & 63;
  int j = lane & 7;

  float v[2]; int ii[2];
#pragma unroll
  for (int p = 0; p < 2; ++p) {
    const u16*   qp = q + (size_t)t * 512 + p * 256 + w * 64;   // broadcast
    const float* kp = keysT + ((size_t)(w * 2 + p) * 64) * 64 + lane;
    float s0 = 0.f, s1 = 0.f, s2 = 0.f, s3 = 0.f;   // 4-way fma ILP
#pragma unroll
    for (int n = 0; n < 64; n += 8) {
      B8 qv; qv.v = *(const short8*)(qp + n);
      s0 += b2f(qv.u[0]) * kp[(size_t)(n + 0) * 64];
      s1 += b2f(qv.u[1]) * kp[(size_t)(n + 1) * 64];
      s2 += b2f(qv.u[2]) * kp[(size_t)(n + 2) * 64];
      s3 += b2f(qv.u[3]) * kp[(size_t)(n + 3) * 64];
      s0 += b2f(qv.u[4]) * kp[(size_t)(n + 4) * 64];
      s1 += b2f(qv.u[5]) * kp[(size_t)(n + 5) * 64];
      s2 += b2f(qv.u[6]) * kp[(size_t)(n + 6) * 64];
      s3 += b2f(qv.u[7]) * kp[(size_t)(n + 7) * 64];
    }
    v[p] = (s0 + s1) + (s2 + s3); ii[p] = lane;
  }

  // phase 1: per-half top-8 of 64 (two interleaved networks)
  sort8_desc<2>(v, ii, j);
  merge_top8<2>(v, ii, j);

  // phase 2: 64 combo sums; groups pre-sorted (sy sorted), merge only
  float v2[1] = { __shfl(v[0], lane >> 3) + __shfl(v[1], lane & 7) };
  int  pos[1] = { lane };                   // combo position = tie-break key
  merge_top8<1>(v2, pos, j);

  int ex = __shfl(ii[0], pos[0] >> 3);
  int ey = __shfl(ii[1], pos[0] & 7);

  float m = __shfl(v2[0], 0);
  float e = __expf(v2[0] - m);
  float sum = e;
#pragma unroll
  for (int s = 4; s > 0; s >>= 1) sum += __shfl_xor(sum, s);

  if (lane < 8) {
    int o = (t * 4 + w) * 8 + lane;
    p_out[o]   = e / sum;
    idx_out[o] = ex * 64 + ey;
  }
}

// ---------------- expert gather + weighted sum (bf16 tables, fp32 acc) -----
__global__ __launch_bounds__(256) void expert_k(
    const u16* __restrict__ xb, const u16* __restrict__ downb,
    const u16* __restrict__ upb,
    const int* __restrict__ idx, const float* __restrict__ probs,
    float* __restrict__ es)     // [4096][1024] fp32
{
  __shared__ float acc_s[4][1024];   // 16 KB
  int t = blockIdx.x;
  int w = threadIdx.x >> 6, lane = threadIdx.x & 63;
  const size_t tb = (size_t)t * 1024;
  const int lo = lane * 8;

  B8 xv0, xv1;
  xv0.v = *(const short8*)(xb + tb + lo);
  xv1.v = *(const short8*)(xb + tb + 512 + lo);
  float xf[16];
#pragma unroll
  for (int c = 0; c < 8; ++c) { xf[c] = b2f(xv0.u[c]); xf[8 + c] = b2f(xv1.u[c]); }

  float a[16] = {};
#pragma unroll
  for (int e8 = 0; e8 < 8; ++e8) {
    int e = w * 8 + e8;
    int id = idx[t * 32 + e];
    const u16* dp = downb + (size_t)id * 1024;
    B8 d0, d1;
    d0.v = *(const short8*)(dp + lo);
    d1.v = *(const short8*)(dp + 512 + lo);
    float part = 0.f;
#pragma unroll
    for (int c = 0; c < 8; ++c)
      part += xf[c] * b2f(d0.u[c]) + xf[8 + c] * b2f(d1.u[c]);
#pragma unroll
    for (int off = 32; off; off >>= 1) part += __shfl_xor(part, off);
    float gate = (part / (1.f + __expf(-part))) * probs[t * 32 + e];
    const u16* upp = upb + (size_t)id * 1024;
    B8 u0, u1;
    u0.v = *(const short8*)(upp + lo);
    u1.v = *(const short8*)(upp + 512 + lo);
#pragma unroll
    for (int c = 0; c < 8; ++c) {
      a[c]     += gate * b2f(u0.u[c]);
      a[8 + c] += gate * b2f(u1.u[c]);
    }
  }
#pragma unroll
  for (int c = 0; c < 8; ++c) {
    acc_s[w][lo + c]       = a[c];
    acc_s[w][512 + lo + c] = a[8 + c];
  }
  __syncthreads();
  int d0i = threadIdx.x * 4;
  f32x4 s0 = *(const f32x4*)(&acc_s[0][d0i]);
  f32x4 s1 = *(const f32x4*)(&acc_s[1][d0i]);
  f32x4 s2 = *(const f32x4*)(&acc_s[2][d0i]);
  f32x4 s3 = *(const f32x4*)(&acc_s[3][d0i]);
  f32x4 o;
#pragma unroll
  for (int c = 0; c < 4; ++c) o[c] = (s0[c] + s1[c]) + (s2[c] + s3[c]);
  *(f32x4*)(es + tb + d0i) = o;
}

extern "C" void kernel_launch(void* const* d_in, const int* in_sizes, int n_in,
                              void* d_out, int out_size, void* d_ws, size_t ws_size,
                              hipStream_t stream)
{
  const float* x    = (const float*)d_in[0];
  const float* Wg   = (const float*)d_in[1];
  const float* bg   = (const float*)d_in[2];
  const float* Wu   = (const float*)d_in[3];
  const float* bu   = (const float*)d_in[4];
  const float* Wd   = (const float*)d_in[5];
  const float* bd   = (const float*)d_in[6];
  const float* Wq   = (const float*)d_in[7];
  const float* keys = (const float*)d_in[8];
  const float* down = (const float*)d_in[9];
  const float* up   = (const float*)d_in[10];
  float* out = (float*)d_out;

  // --- workspace layout ---
  const size_t MB = 1048576;
  char* ws = (char*)d_ws;
  u16*   xb    = (u16*)(ws);                 // 8 MB  bf16 x [4096][1024]
  u16*   WgT   = (u16*)(ws + 8  * MB);       // 8 MB  bf16 [4096][1024]
  u16*   WuT   = (u16*)(ws + 16 * MB);       // 8 MB
  u16*   WdT   = (u16*)(ws + 24 * MB);       // 8 MB  bf16 [1024][4096]
  float* es    = (float*)(ws + 32 * MB);     // 16 MB fp32 [4096][1024]
  u16*   WqT   = (u16*)(ws + 32 * MB);       // 1 MB, aliases es head (dead first)
  u16*   qb    = (u16*)(ws + 34 * MB);       // 4 MB, aliases es (dead first)
  float* keysT = (float*)(ws + 47 * MB);     // 128 KB, aliases es tail (dead first)
  int*   idxb  = (int*)(ws + 48 * MB);       // 512 KB
  float* prb   = (float*)(ws + 48 * MB + 512 * 1024);
  u16*   downb = (u16*)(ws + 49 * MB);       // 8 MB bf16 [4096][1024]
  u16*   upb   = (u16*)(ws + 57 * MB);       // 8 MB

  // split-K partials for down-GEMM: S x 16 MB fp32 [4096][1024], then gb
  int S = 2;
  while (S > 1 && 65 * MB + (size_t)S * 16 * MB + 1 * MB > ws_size) S >>= 1;
  float* part = (float*)(ws + 65 * MB);
  size_t gboff = 65 * MB + (size_t)S * 16 * MB;
  u16*   gb    = (u16*)(ws + gboff);         // chunk_rows x 4096 bf16 (h1)

  size_t avail = ws_size > gboff ? ws_size - gboff : 0;
  int rows = 4096;                           // rows per MLP chunk
  while (rows > 128 && (size_t)rows * 4096 * 2 > avail) rows >>= 1;
  int Ksl = 4096 / S;

  // conversions (fp32 -> bf16; weights fused with transpose)
  cvt_f2b<<<4096, 256, 0, stream>>>(x, xb);
  cvt_f2b<<<4096, 256, 0, stream>>>(down, downb);
  cvt_f2b<<<4096, 256, 0, stream>>>(up, upb);
  convt_w<<<dim3(16, 16),  256, 0, stream>>>(Wq, WqT, 1024, 512);
  convt_w<<<dim3(16, 128), 256, 0, stream>>>(Wg, WgT, 1024, 4096);
  convt_w<<<dim3(16, 128), 256, 0, stream>>>(Wu, WuT, 1024, 4096);
  convt_w<<<dim3(64, 32),  256, 0, stream>>>(Wd, WdT, 4096, 1024);
  convt_keys<<<dim3(4, 2), 256, 0, stream>>>(keys, keysT);

  // retrieval chain: q = x@Wq -> topk experts -> es
  gemm_bf16<<<dim3(4, 32), 256, 0, stream>>>(xb, WqT, nullptr,
                                             qb, 4096, 512, 1024);
  retrieve_k<<<4096, 256, 0, stream>>>(qb, keysT, idxb, prb);
  expert_k<<<4096, 256, 0, stream>>>(xb, downb, upb, idxb, prb, es);

  // MLP chain: h1 = silu(x@Wg+bg)*(x@Wu+bu); P[s] = h1@Wd (split-K stores)
  for (int m0c = 0; m0c < 4096; m0c += rows) {
    int gy = rows / 128;
    gemm_gu<<<dim3(32, gy), 256, 0, stream>>>(xb + (size_t)m0c * 1024, WgT, WuT,
                                              bg, bu, gb, rows, 4096, 1024);
    gemm_dsk<<<dim3(8, gy, S), 256, 0, stream>>>(gb, WdT, part,
                                                 rows, 1024, 4096, Ksl, m0c);
  }
  // fused epilogue: out = sum_s P[s] + es + bd
  reduce_k<<<4096, 256, 0, stream>>>(part, S, es, bd, out);
}

// Round 10
// 400.380 us; speedup vs baseline: 1.2290x; 1.0185x over previous
//
#include <hip/hip_runtime.h>
#include <hip/hip_bf16.h>
#include <stdint.h>

typedef unsigned short u16;
typedef __attribute__((ext_vector_type(8))) short short8;   // 8 bf16 (4 VGPRs)
typedef __attribute__((ext_vector_type(4))) float f32x4;
typedef __attribute__((ext_vector_type(2))) float f32x2;

union B8 { short8 v; u16 u[8]; };
union U4 { unsigned long long q; u16 u[4]; };

__device__ __forceinline__ float b2f(u16 b) {
  union { unsigned int i; float f; } x; x.i = ((unsigned int)b) << 16; return x.f;
}
__device__ __forceinline__ u16 f2b(float f) {
  __hip_bfloat16 h = __float2bfloat16(f);
  return *reinterpret_cast<u16*>(&h);
}

// async global->LDS, 16B/lane, LDS dest = wave-uniform base + lane*16 [m97]
#define GLOAD_LDS16(gp, lp)                                                  \
  __builtin_amdgcn_global_load_lds(                                          \
      (const __attribute__((address_space(1))) unsigned int*)(gp),           \
      (__attribute__((address_space(3))) unsigned int*)(lp), 16, 0, 0)

// ---------------- convert fp32 -> bf16 (elementwise, n % 1024 == 0) --------
__global__ __launch_bounds__(256) void cvt_f2b(const float* __restrict__ src,
                                               u16* __restrict__ dst) {
  size_t i = ((size_t)blockIdx.x * 256 + threadIdx.x) * 4;
  f32x4 v = *(const f32x4*)(src + i);
  U4 o;
#pragma unroll
  for (int j = 0; j < 4; ++j) o.u[j] = f2b(v[j]);
  *(unsigned long long*)(dst + i) = o.q;
}

// ---------------- convert + transpose: fp32 W[K][N] -> bf16 WT[N][K] -------
__global__ __launch_bounds__(256) void convt_w(const float* __restrict__ W,
                                               u16* __restrict__ WT,
                                               int K, int N) {
  int k  = blockIdx.x * 64 + (threadIdx.x & 63);
  int n8 = blockIdx.y * 32 + (threadIdx.x >> 6) * 8;
  const float* p = W + (size_t)k * N + n8;
  f32x4 a = *(const f32x4*)(p);
  f32x4 b = *(const f32x4*)(p + 4);
#pragma unroll
  for (int j = 0; j < 4; ++j) WT[(size_t)(n8 + j) * K + k] = f2b(a[j]);
#pragma unroll
  for (int j = 0; j < 4; ++j) WT[(size_t)(n8 + 4 + j) * K + k] = f2b(b[j]);
}

// ------ keys transpose: fp32 [H=4][K=64][P=2][N=64] -> [H][P][N][K] --------
__global__ __launch_bounds__(256) void convt_keys(const float* __restrict__ keys,
                                                  float* __restrict__ keysT) {
  int h = blockIdx.x, p = blockIdx.y;
  int k  = threadIdx.x >> 2;            // 0..63
  int n0 = (threadIdx.x & 3) * 16;      // 0,16,32,48
  const float* src = keys + ((size_t)(h * 64 + k) * 2 + p) * 64 + n0;
  float* dst = keysT + (((size_t)h * 2 + p) * 64) * 64 + k;
#pragma unroll
  for (int c = 0; c < 16; ++c)
    dst[(size_t)(n0 + c) * 64] = src[c];
}

// ------- small GEMM (q-projection), BK=64 + swizzle [r9-proven] ------------
__global__ __launch_bounds__(256) void gemm_bf16(
    const u16* __restrict__ A, const u16* __restrict__ BT,
    const float* __restrict__ bias,
    u16* __restrict__ Cb, int M, int N, int K)
{
  __shared__ __attribute__((aligned(16))) u16 As[128 * 64];
  __shared__ __attribute__((aligned(16))) u16 Bs[128 * 64];
  int tid = threadIdx.x;
  int m0 = blockIdx.y * 128, n0 = blockIdx.x * 128;
  int wave = tid >> 6, lane = tid & 63;
  int wm = (wave >> 1) * 64, wn = (wave & 1) * 64;
  int quad = lane >> 4, r16 = lane & 15;
  int s7 = r16 & 7;

  int srow = lane >> 3;
  int scol = ((lane & 7) ^ srow) * 8;
  const u16* aG = A  + (size_t)(m0 + wave * 32 + srow) * K + scol;
  const u16* bG = BT + (size_t)(n0 + wave * 32 + srow) * K + scol;

  f32x4 acc[4][4] = {};

  for (int k0 = 0; k0 < K; k0 += 64) {
#pragma unroll
    for (int idx = 0; idx < 4; ++idx) {
      size_t go = (size_t)idx * 8 * K + k0;
      int lo = wave * 2048 + idx * 512;
      GLOAD_LDS16(aG + go, As + lo);
      GLOAD_LDS16(bG + go, Bs + lo);
    }
    __syncthreads();
#pragma unroll
    for (int kk = 0; kk < 2; ++kk) {
      short8 af[4], bfr[4];
#pragma unroll
      for (int i = 0; i < 4; ++i)
        af[i] = *(const short8*)(&As[(wm + i * 16 + r16) * 64
                                     + (((kk << 2) + quad) ^ s7) * 8]);
#pragma unroll
      for (int j = 0; j < 4; ++j)
        bfr[j] = *(const short8*)(&Bs[(wn + j * 16 + r16) * 64
                                      + (((kk << 2) + quad) ^ s7) * 8]);
#pragma unroll
      for (int i = 0; i < 4; ++i)
#pragma unroll
        for (int j = 0; j < 4; ++j)
          acc[i][j] = __builtin_amdgcn_mfma_f32_16x16x32_bf16(af[i], bfr[j], acc[i][j], 0, 0, 0);
    }
    __syncthreads();
  }

  // C/D layout: col = lane&15, row = quad*4 + reg   [m89-verified]
#pragma unroll
  for (int i = 0; i < 4; ++i) {
    int row = m0 + wm + i * 16 + quad * 4;
#pragma unroll
    for (int j = 0; j < 4; ++j) {
      int col = n0 + wn + j * 16 + r16;
      float bv = bias ? bias[col] : 0.f;
#pragma unroll
      for (int r = 0; r < 4; ++r) {
        float v = acc[i][j][r] + bv;
        Cb[(size_t)(row + r) * N + col] = f2b(v);
      }
    }
  }
}

// ------- fused gate+up GEMM, BK=64 [r9-proven: 68.4us, MfmaUtil 43%] -------
__global__ __launch_bounds__(256, 2) void gemm_gu(
    const u16* __restrict__ A, const u16* __restrict__ BgT,
    const u16* __restrict__ BuT,
    const float* __restrict__ bg, const float* __restrict__ bu,
    u16* __restrict__ H, int M, int N, int K)
{
  __shared__ __attribute__((aligned(16))) u16 As[128 * 64];
  __shared__ __attribute__((aligned(16))) u16 Gs[128 * 64];
  __shared__ __attribute__((aligned(16))) u16 Us[128 * 64];
  int tid = threadIdx.x;
  int m0 = blockIdx.y * 128, n0 = blockIdx.x * 128;
  int wave = tid >> 6, lane = tid & 63;
  int wm = (wave >> 1) * 64, wn = (wave & 1) * 64;
  int quad = lane >> 4, r16 = lane & 15;
  int s7 = r16 & 7;

  int srow = lane >> 3;
  int scol = ((lane & 7) ^ srow) * 8;
  const u16* aG = A   + (size_t)(m0 + wave * 32 + srow) * K + scol;
  const u16* gG = BgT + (size_t)(n0 + wave * 32 + srow) * K + scol;
  const u16* uG = BuT + (size_t)(n0 + wave * 32 + srow) * K + scol;

  f32x4 ag[4][4] = {}, au[4][4] = {};

  for (int k0 = 0; k0 < K; k0 += 64) {
#pragma unroll
    for (int idx = 0; idx < 4; ++idx) {
      size_t go = (size_t)idx * 8 * K + k0;
      int lo = wave * 2048 + idx * 512;
      GLOAD_LDS16(aG + go, As + lo);
      GLOAD_LDS16(gG + go, Gs + lo);
      GLOAD_LDS16(uG + go, Us + lo);
    }
    __syncthreads();
#pragma unroll
    for (int kk = 0; kk < 2; ++kk) {
      short8 af[4], bfr[4];
#pragma unroll
      for (int i = 0; i < 4; ++i)
        af[i] = *(const short8*)(&As[(wm + i * 16 + r16) * 64
                                     + (((kk << 2) + quad) ^ s7) * 8]);
#pragma unroll
      for (int j = 0; j < 4; ++j)
        bfr[j] = *(const short8*)(&Gs[(wn + j * 16 + r16) * 64
                                      + (((kk << 2) + quad) ^ s7) * 8]);
#pragma unroll
      for (int i = 0; i < 4; ++i)
#pragma unroll
        for (int j = 0; j < 4; ++j)
          ag[i][j] = __builtin_amdgcn_mfma_f32_16x16x32_bf16(af[i], bfr[j], ag[i][j], 0, 0, 0);
#pragma unroll
      for (int j = 0; j < 4; ++j)
        bfr[j] = *(const short8*)(&Us[(wn + j * 16 + r16) * 64
                                      + (((kk << 2) + quad) ^ s7) * 8]);
#pragma unroll
      for (int i = 0; i < 4; ++i)
#pragma unroll
        for (int j = 0; j < 4; ++j)
          au[i][j] = __builtin_amdgcn_mfma_f32_16x16x32_bf16(af[i], bfr[j], au[i][j], 0, 0, 0);
    }
    __syncthreads();
  }

#pragma unroll
  for (int i = 0; i < 4; ++i) {
    int row = m0 + wm + i * 16 + quad * 4;
#pragma unroll
    for (int j = 0; j < 4; ++j) {
      int col = n0 + wn + j * 16 + r16;
      float bgv = bg[col], buv = bu[col];
#pragma unroll
      for (int r = 0; r < 4; ++r) {
        float g = ag[i][j][r] + bgv;
        float u = au[i][j][r] + buv;
        float h = (g / (1.f + __expf(-g))) * u;
        H[(size_t)(row + r) * N + col] = f2b(h);
      }
    }
  }
}

// -------- split-K down-GEMM, BK=64, XCD-aware [T1+r9-proven] ---------------
__global__ __launch_bounds__(256) void gemm_dsk(
    const u16* __restrict__ A, const u16* __restrict__ BT,
    float* __restrict__ P, int M, int N, int K, int Kslice, int mOff)
{
  __shared__ __attribute__((aligned(16))) u16 As[128 * 64];
  __shared__ __attribute__((aligned(16))) u16 Bs[128 * 64];
  int tid = threadIdx.x;

  int lid = blockIdx.x + blockIdx.y * gridDim.x +
            blockIdx.z * gridDim.x * gridDim.y;
  int G = gridDim.y * gridDim.z;          // (m,z) groups; n = gridDim.x = 8
  int n_blk, m_blk, z_blk;
  if ((G & 7) == 0) {
    int x = lid & 7, s = lid >> 3;        // XCD, per-XCD slot
    int gid = x * (G >> 3) + (s >> 3);    // group handled by this XCD
    n_blk = s & 7;
    m_blk = gid % gridDim.y;
    z_blk = gid / gridDim.y;
  } else {
    n_blk = blockIdx.x; m_blk = blockIdx.y; z_blk = blockIdx.z;
  }

  int m0 = m_blk * 128, n0 = n_blk * 128;
  int kb = z_blk * Kslice, ke = kb + Kslice;
  int wave = tid >> 6, lane = tid & 63;
  int wm = (wave >> 1) * 64, wn = (wave & 1) * 64;
  int quad = lane >> 4, r16 = lane & 15;
  int s7 = r16 & 7;

  int srow = lane >> 3;
  int scol = ((lane & 7) ^ srow) * 8;
  const u16* aG = A  + (size_t)(m0 + wave * 32 + srow) * K + scol;
  const u16* bG = BT + (size_t)(n0 + wave * 32 + srow) * K + scol;

  f32x4 acc[4][4] = {};

  for (int k0 = kb; k0 < ke; k0 += 64) {
#pragma unroll
    for (int idx = 0; idx < 4; ++idx) {
      size_t go = (size_t)idx * 8 * K + k0;
      int lo = wave * 2048 + idx * 512;
      GLOAD_LDS16(aG + go, As + lo);
      GLOAD_LDS16(bG + go, Bs + lo);
    }
    __syncthreads();
#pragma unroll
    for (int kk = 0; kk < 2; ++kk) {
      short8 af[4], bfr[4];
#pragma unroll
      for (int i = 0; i < 4; ++i)
        af[i] = *(const short8*)(&As[(wm + i * 16 + r16) * 64
                                     + (((kk << 2) + quad) ^ s7) * 8]);
#pragma unroll
      for (int j = 0; j < 4; ++j)
        bfr[j] = *(const short8*)(&Bs[(wn + j * 16 + r16) * 64
                                      + (((kk << 2) + quad) ^ s7) * 8]);
#pragma unroll
      for (int i = 0; i < 4; ++i)
#pragma unroll
        for (int j = 0; j < 4; ++j)
          acc[i][j] = __builtin_amdgcn_mfma_f32_16x16x32_bf16(af[i], bfr[j], acc[i][j], 0, 0, 0);
    }
    __syncthreads();
  }

  float* Pz = P + (size_t)z_blk * 4194304;   // 4096*1024 per slice
#pragma unroll
  for (int i = 0; i < 4; ++i) {
    int row = mOff + m0 + wm + i * 16 + quad * 4;
#pragma unroll
    for (int j = 0; j < 4; ++j) {
      int col = n0 + wn + j * 16 + r16;
#pragma unroll
      for (int r = 0; r < 4; ++r)
        Pz[(size_t)(row + r) * N + col] = acc[i][j][r];
    }
  }
}

// ------- fused reduce: out = sum_s P[s] + es + bd (N = 1024) ---------------
__global__ __launch_bounds__(256) void reduce_k(const float* __restrict__ part,
                                                int S,
                                                const float* __restrict__ es,
                                                const float* __restrict__ bd,
                                                float* __restrict__ out) {
  int t = blockIdx.x, c0 = threadIdx.x * 4;
  size_t off = (size_t)t * 1024 + c0;
  f32x4 a = *(const f32x4*)(es + off);
  for (int s = 0; s < S; ++s) {
    f32x4 p = *(const f32x4*)(part + (size_t)s * 4194304 + off);
#pragma unroll
    for (int c = 0; c < 4; ++c) a[c] += p[c];
  }
  f32x4 b = *(const f32x4*)(bd + c0);
  f32x4 o;
#pragma unroll
  for (int c = 0; c < 4; ++c) o[c] = a[c] + b[c];
  *(f32x4*)(out + off) = o;
}

// ======== bitonic top-8-of-64 network helpers (values spread 1/lane) =======
template<int NP>
__device__ __forceinline__ void sort8_desc(float (&v)[NP], int (&ii)[NP], int j) {
#pragma unroll
  for (int k = 2; k <= 8; k <<= 1) {
#pragma unroll
    for (int s = k >> 1; s > 0; s >>= 1) {
      bool desc  = (j & k) == 0;
      bool lower = (j & s) == 0;
#pragma unroll
      for (int p = 0; p < NP; ++p) {
        float vp = __shfl_xor(v[p], s);
        int   ip = __shfl_xor(ii[p], s);
        bool mf = (v[p] > vp) || (v[p] == vp && ii[p] < ip);
        bool keep = (desc == lower) ? mf : !mf;
        if (!keep) { v[p] = vp; ii[p] = ip; }
      }
    }
  }
}

template<int NP>
__device__ __forceinline__ void merge_top8(float (&v)[NP], int (&ii)[NP], int j) {
#pragma unroll
  for (int r = 0; r < 3; ++r) {
    int mask = (8 << r) | 7;     // partner group, mirrored position
#pragma unroll
    for (int p = 0; p < NP; ++p) {
      float vp = __shfl_xor(v[p], mask);
      int   ip = __shfl_xor(ii[p], mask);
      bool mf = (v[p] > vp) || (v[p] == vp && ii[p] < ip);
      if (!mf) { v[p] = vp; ii[p] = ip; }   // elementwise max -> bitonic seq
    }
#pragma unroll
    for (int s = 4; s > 0; s >>= 1) {       // bitonic merge, descending
      bool lower = (j & s) == 0;
#pragma unroll
      for (int p = 0; p < NP; ++p) {
        float vq = __shfl_xor(v[p], s);
        int   iq = __shfl_xor(ii[p], s);
        bool mf = (v[p] > vq) || (v[p] == vq && ii[p] < iq);
        bool keep = lower ? mf : !mf;
        if (!keep) { v[p] = vq; ii[p] = iq; }
      }
    }
  }
}

// ---------------- product-key retrieval (bitonic top-k, in-register) -------
__global__ __launch_bounds__(256) void retrieve_k(
    const u16*  __restrict__ q,      // bf16 [4096][512] = [t][p(2)][h(4)][n(64)]
    const float* __restrict__ keysT, // fp32 [4][2][64][64] = [h][p][n][k]
    int* __restrict__ idx_out,       // [4096][4][8]
    float* __restrict__ p_out)       // [4096][4][8]
{
  int t = blockIdx.x;
  int w = threadIdx.x >> 6, lane = threadIdx.x & 63;
  int j = lane & 7;

  float v[2]; int ii[2];
#pragma unroll
  for (int p = 0; p < 2; ++p) {
    const u16*   qp = q + (size_t)t * 512 + p * 256 + w * 64;   // broadcast
    const float* kp = keysT + ((size_t)(w * 2 + p) * 64) * 64 + lane;
    float s0 = 0.f, s1 = 0.f, s2 = 0.f, s3 = 0.f;   // 4-way fma ILP
#pragma unroll
    for (int n = 0; n < 64; n += 8) {
      B8 qv; qv.v = *(const short8*)(qp + n);
      s0 += b2f(qv.u[0]) * kp[(size_t)(n + 0) * 64];
      s1 += b2f(qv.u[1]) * kp[(size_t)(n + 1) * 64];
      s2 += b2f(qv.u[2]) * kp[(size_t)(n + 2) * 64];
      s3 += b2f(qv.u[3]) * kp[(size_t)(n + 3) * 64];
      s0 += b2f(qv.u[4]) * kp[(size_t)(n + 4) * 64];
      s1 += b2f(qv.u[5]) * kp[(size_t)(n + 5) * 64];
      s2 += b2f(qv.u[6]) * kp[(size_t)(n + 6) * 64];
      s3 += b2f(qv.u[7]) * kp[(size_t)(n + 7) * 64];
    }
    v[p] = (s0 + s1) + (s2 + s3); ii[p] = lane;
  }

  // phase 1: per-half top-8 of 64 (two interleaved networks)
  sort8_desc<2>(v, ii, j);
  merge_top8<2>(v, ii, j);

  // phase 2: 64 combo sums; groups pre-sorted (sy sorted), merge only
  float v2[1] = { __shfl(v[0], lane >> 3) + __shfl(v[1], lane & 7) };
  int  pos[1] = { lane };                   // combo position = tie-break key
  merge_top8<1>(v2, pos, j);

  int ex = __shfl(ii[0], pos[0] >> 3);
  int ey = __shfl(ii[1], pos[0] & 7);

  float m = __shfl(v2[0], 0);
  float e = __expf(v2[0] - m);
  float sum = e;
#pragma unroll
  for (int s = 4; s > 0; s >>= 1) sum += __shfl_xor(sum, s);

  if (lane < 8) {
    int o = (t * 4 + w) * 8 + lane;
    p_out[o]   = e / sum;
    idx_out[o] = ex * 64 + ey;
  }
}

// ---------- expert gather + weighted sum: 8 waves, 4 experts/wave ----------
// r10: halve the per-wave serial chain (8 -> 4 expert iterations of
// load -> 6-shuffle reduce -> gate -> load -> accumulate). 512 thr, 32KB LDS
// -> 4 blocks/CU, full 32-wave occupancy.
__global__ __launch_bounds__(512) void expert_k(
    const u16* __restrict__ xb, const u16* __restrict__ downb,
    const u16* __restrict__ upb,
    const int* __restrict__ idx, const float* __restrict__ probs,
    float* __restrict__ es)     // [4096][1024] fp32
{
  __shared__ float acc_s[8][1024];   // 32 KB
  int t = blockIdx.x;
  int w = threadIdx.x >> 6, lane = threadIdx.x & 63;
  const size_t tb = (size_t)t * 1024;
  const int lo = lane * 8;

  B8 xv0, xv1;
  xv0.v = *(const short8*)(xb + tb + lo);
  xv1.v = *(const short8*)(xb + tb + 512 + lo);
  float xf[16];
#pragma unroll
  for (int c = 0; c < 8; ++c) { xf[c] = b2f(xv0.u[c]); xf[8 + c] = b2f(xv1.u[c]); }

  float a[16] = {};
#pragma unroll
  for (int e4 = 0; e4 < 4; ++e4) {
    int e = w * 4 + e4;
    int id = idx[t * 32 + e];
    const u16* dp = downb + (size_t)id * 1024;
    B8 d0, d1;
    d0.v = *(const short8*)(dp + lo);
    d1.v = *(const short8*)(dp + 512 + lo);
    float part = 0.f;
#pragma unroll
    for (int c = 0; c < 8; ++c)
      part += xf[c] * b2f(d0.u[c]) + xf[8 + c] * b2f(d1.u[c]);
#pragma unroll
    for (int off = 32; off; off >>= 1) part += __shfl_xor(part, off);
    float gate = (part / (1.f + __expf(-part))) * probs[t * 32 + e];
    const u16* upp = upb + (size_t)id * 1024;
    B8 u0, u1;
    u0.v = *(const short8*)(upp + lo);
    u1.v = *(const short8*)(upp + 512 + lo);
#pragma unroll
    for (int c = 0; c < 8; ++c) {
      a[c]     += gate * b2f(u0.u[c]);
      a[8 + c] += gate * b2f(u1.u[c]);
    }
  }
#pragma unroll
  for (int c = 0; c < 8; ++c) {
    acc_s[w][lo + c]       = a[c];
    acc_s[w][512 + lo + c] = a[8 + c];
  }
  __syncthreads();
  // 512 threads x 2 floats = 1024 cols; 8-way partial sum
  int d0i = threadIdx.x * 2;
  float o0 = 0.f, o1 = 0.f;
#pragma unroll
  for (int ww = 0; ww < 8; ++ww) {
    o0 += acc_s[ww][d0i];
    o1 += acc_s[ww][d0i + 1];
  }
  f32x2 o; o[0] = o0; o[1] = o1;
  *(f32x2*)(es + tb + d0i) = o;
}

extern "C" void kernel_launch(void* const* d_in, const int* in_sizes, int n_in,
                              void* d_out, int out_size, void* d_ws, size_t ws_size,
                              hipStream_t stream)
{
  const float* x    = (const float*)d_in[0];
  const float* Wg   = (const float*)d_in[1];
  const float* bg   = (const float*)d_in[2];
  const float* Wu   = (const float*)d_in[3];
  const float* bu   = (const float*)d_in[4];
  const float* Wd   = (const float*)d_in[5];
  const float* bd   = (const float*)d_in[6];
  const float* Wq   = (const float*)d_in[7];
  const float* keys = (const float*)d_in[8];
  const float* down = (const float*)d_in[9];
  const float* up   = (const float*)d_in[10];
  float* out = (float*)d_out;

  // --- workspace layout ---
  const size_t MB = 1048576;
  char* ws = (char*)d_ws;
  u16*   xb    = (u16*)(ws);                 // 8 MB  bf16 x [4096][1024]
  u16*   WgT   = (u16*)(ws + 8  * MB);       // 8 MB  bf16 [4096][1024]
  u16*   WuT   = (u16*)(ws + 16 * MB);       // 8 MB
  u16*   WdT   = (u16*)(ws + 24 * MB);       // 8 MB  bf16 [1024][4096]
  float* es    = (float*)(ws + 32 * MB);     // 16 MB fp32 [4096][1024]
  u16*   WqT   = (u16*)(ws + 32 * MB);       // 1 MB, aliases es head (dead first)
  u16*   qb    = (u16*)(ws + 34 * MB);       // 4 MB, aliases es (dead first)
  float* keysT = (float*)(ws + 47 * MB);     // 128 KB, aliases es tail (dead first)
  int*   idxb  = (int*)(ws + 48 * MB);       // 512 KB
  float* prb   = (float*)(ws + 48 * MB + 512 * 1024);
  u16*   downb = (u16*)(ws + 49 * MB);       // 8 MB bf16 [4096][1024]
  u16*   upb   = (u16*)(ws + 57 * MB);       // 8 MB

  // split-K partials for down-GEMM: S x 16 MB fp32 [4096][1024], then gb
  int S = 2;
  while (S > 1 && 65 * MB + (size_t)S * 16 * MB + 1 * MB > ws_size) S >>= 1;
  float* part = (float*)(ws + 65 * MB);
  size_t gboff = 65 * MB + (size_t)S * 16 * MB;
  u16*   gb    = (u16*)(ws + gboff);         // chunk_rows x 4096 bf16 (h1)

  size_t avail = ws_size > gboff ? ws_size - gboff : 0;
  int rows = 4096;                           // rows per MLP chunk
  while (rows > 128 && (size_t)rows * 4096 * 2 > avail) rows >>= 1;
  int Ksl = 4096 / S;

  // conversions (fp32 -> bf16; weights fused with transpose)
  cvt_f2b<<<4096, 256, 0, stream>>>(x, xb);
  cvt_f2b<<<4096, 256, 0, stream>>>(down, downb);
  cvt_f2b<<<4096, 256, 0, stream>>>(up, upb);
  convt_w<<<dim3(16, 16),  256, 0, stream>>>(Wq, WqT, 1024, 512);
  convt_w<<<dim3(16, 128), 256, 0, stream>>>(Wg, WgT, 1024, 4096);
  convt_w<<<dim3(16, 128), 256, 0, stream>>>(Wu, WuT, 1024, 4096);
  convt_w<<<dim3(64, 32),  256, 0, stream>>>(Wd, WdT, 4096, 1024);
  convt_keys<<<dim3(4, 2), 256, 0, stream>>>(keys, keysT);

  // retrieval chain: q = x@Wq -> topk experts -> es
  gemm_bf16<<<dim3(4, 32), 256, 0, stream>>>(xb, WqT, nullptr,
                                             qb, 4096, 512, 1024);
  retrieve_k<<<4096, 256, 0, stream>>>(qb, keysT, idxb, prb);
  expert_k<<<4096, 512, 0, stream>>>(xb, downb, upb, idxb, prb, es);

  // MLP chain: h1 = silu(x@Wg+bg)*(x@Wu+bu); P[s] = h1@Wd (split-K stores)
  for (int m0c = 0; m0c < 4096; m0c += rows) {
    int gy = rows / 128;
    gemm_gu<<<dim3(32, gy), 256, 0, stream>>>(xb + (size_t)m0c * 1024, WgT, WuT,
                                              bg, bu, gb, rows, 4096, 1024);
    gemm_dsk<<<dim3(8, gy, S), 256, 0, stream>>>(gb, WdT, part,
                                                 rows, 1024, 4096, Ksl, m0c);
  }
  // fused epilogue: out = sum_s P[s] + es + bd
  reduce_k<<<4096, 256, 0, stream>>>(part, S, es, bd, out);
}